// Round 1
// baseline (537.976 us; speedup 1.0000x reference)
//
#include <hip/hip_runtime.h>
#include <hip/hip_bf16.h>
#include <math.h>

// Problem constants (fixed by the reference's setup_inputs):
//   x: (4, 64, 128, 128)  y: (8, 64, 128, 128)
//   G=4 groups, cg=dc=16, K=3 (K2=9), dilation per group = 2g+1
//   out: (8, 64, 9, 128, 128) fp32
constexpr int HH   = 128;
constexpr int WW   = 128;
constexpr int HWsz = HH * WW;          // 16384

// ---- workspace layout (in floats) ----
constexpr long OFFS_OFF = 0;                            // offsets [4][4][18][HW]
constexpr long MASK_OFF = OFFS_OFF + 4L * 4 * 18 * HWsz; // mask   [4][9][HW]
constexpr long WEO_OFF  = MASK_OFF + 4L * 9 * HWsz;      // Weff_off  [4][16][9][18]
constexpr long WRO_OFF  = WEO_OFF + 4L * 16 * 9 * 18;    // Wraw_off  [4][48][18]
constexpr long WEM_OFF  = WRO_OFF + 4L * 48 * 18;        // Weff_mask [16][9][9]
constexpr long WRM_OFF  = WEM_OFF + 16L * 9 * 9;         // Wraw_mask [48][9]

// -------------------------------------------------------------------------
// Kernel 0: collapse (3x3 conv 16->16) ∘ (1x1 over first-16 channels) into a
// single effective 3x3 conv 16->O, and transpose the raw-channel 1x1 weights
// so the output channel is contiguous (enables scalar dwordx8/x16 loads).
// -------------------------------------------------------------------------
__global__ __launch_bounds__(256) void prep_kernel(
    const float* __restrict__ off_pw,   // (4,16,16,3,3)
    const float* __restrict__ off_w,    // (4,18,64)
    const float* __restrict__ mask_pw,  // (16,16,3,3)
    const float* __restrict__ mask_w,   // (9,64)
    float* __restrict__ Weff_off, float* __restrict__ Wraw_off,
    float* __restrict__ Weff_mask, float* __restrict__ Wraw_mask)
{
    const int i = blockIdx.x * 256 + threadIdx.x;
    if (i < 10368) {                       // Weff_off[g][ci][t][o]
        const int o = i % 18; int r = i / 18;
        const int t = r % 9;  r /= 9;
        const int ci = r % 16; const int g = r / 16;
        float s = 0.f;
        for (int co = 0; co < 16; ++co)
            s += off_w[(g * 18 + o) * 64 + co] *
                 off_pw[((g * 16 + co) * 16 + ci) * 9 + t];
        Weff_off[i] = s;
    } else if (i < 10368 + 3456) {         // Wraw_off[g][c][o]
        const int j = i - 10368;
        const int o = j % 18; int r = j / 18;
        const int c = r % 48; const int g = r / 48;
        Wraw_off[j] = off_w[(g * 18 + o) * 64 + 16 + c];
    } else if (i < 10368 + 3456 + 1296) {  // Weff_mask[ci][t][o]
        const int j = i - 13824;
        const int o = j % 9; int r = j / 9;
        const int t = r % 9; const int ci = r / 9;
        float s = 0.f;
        for (int co = 0; co < 16; ++co)
            s += mask_w[o * 64 + co] * mask_pw[((co * 16) + ci) * 9 + t];
        Weff_mask[j] = s;
    } else if (i < 10368 + 3456 + 1296 + 432) { // Wraw_mask[c][o]
        const int j = i - 15120;
        const int o = j % 9; const int c = j / 9;
        Wraw_mask[j] = mask_w[o * 64 + 16 + c];
    }
}

// -------------------------------------------------------------------------
// Kernel 1: offset + mask fields. One thread per pixel, blockIdx.z selects
// the pass (g=0..3 offsets, 4 = mask). Weight indices are wave-uniform ->
// scalar loads; pixel loads coalesced; 18 independent accumulators for ILP.
// -------------------------------------------------------------------------
__global__ __launch_bounds__(256) void field_kernel(
    const float* __restrict__ x,
    const float* __restrict__ Weff_off, const float* __restrict__ Wraw_off,
    const float* __restrict__ off_b,
    const float* __restrict__ Weff_mask, const float* __restrict__ Wraw_mask,
    const float* __restrict__ mask_b,
    float* __restrict__ offs, float* __restrict__ maskf)
{
    const int p    = blockIdx.x * 256 + threadIdx.x;   // pixel 0..16383
    const int bx   = blockIdx.y;                        // x batch 0..3
    const int pass = blockIdx.z;                        // 0..3 = offs g, 4 = mask
    const int h = p >> 7, w = p & 127;
    const float* xb = x + (long)bx * 64 * HWsz;

    if (pass < 4) {
        const int g = pass;
        float acc[18];
        #pragma unroll
        for (int o = 0; o < 18; ++o) acc[o] = off_b[g * 18 + o];
        // effective 3x3 conv over first 16 channels (zero pad)
        for (int ci = 0; ci < 16; ++ci) {
            const float* xp = xb + ci * HWsz;
            #pragma unroll
            for (int t = 0; t < 9; ++t) {
                const int hh = h + t / 3 - 1, w2 = w + t % 3 - 1;
                float xv = 0.f;
                if ((unsigned)hh < 128u && (unsigned)w2 < 128u)
                    xv = xp[hh * 128 + w2];
                const float* wp = Weff_off + ((g * 16 + ci) * 9 + t) * 18;
                #pragma unroll
                for (int o = 0; o < 18; ++o) acc[o] = fmaf(xv, wp[o], acc[o]);
            }
        }
        // 1x1 over untouched channels 16..63
        for (int c = 0; c < 48; ++c) {
            const float xv = xb[(16 + c) * HWsz + p];
            const float* wp = Wraw_off + (g * 48 + c) * 18;
            #pragma unroll
            for (int o = 0; o < 18; ++o) acc[o] = fmaf(xv, wp[o], acc[o]);
        }
        float* op = offs + ((long)(bx * 4 + g) * 18) * HWsz + p;
        #pragma unroll
        for (int o = 0; o < 18; ++o) op[(long)o * HWsz] = acc[o];
    } else {
        float acc[9];
        #pragma unroll
        for (int o = 0; o < 9; ++o) acc[o] = mask_b[o];
        for (int ci = 0; ci < 16; ++ci) {
            const float* xp = xb + ci * HWsz;
            #pragma unroll
            for (int t = 0; t < 9; ++t) {
                const int hh = h + t / 3 - 1, w2 = w + t % 3 - 1;
                float xv = 0.f;
                if ((unsigned)hh < 128u && (unsigned)w2 < 128u)
                    xv = xp[hh * 128 + w2];
                const float* wp = Weff_mask + (ci * 9 + t) * 9;
                #pragma unroll
                for (int o = 0; o < 9; ++o) acc[o] = fmaf(xv, wp[o], acc[o]);
            }
        }
        for (int c = 0; c < 48; ++c) {
            const float xv = xb[(16 + c) * HWsz + p];
            const float* wp = Wraw_mask + c * 9;
            #pragma unroll
            for (int o = 0; o < 9; ++o) acc[o] = fmaf(xv, wp[o], acc[o]);
        }
        float* op = maskf + (long)bx * 9 * HWsz + p;
        #pragma unroll
        for (int o = 0; o < 9; ++o)
            op[(long)o * HWsz] = 1.0f / (1.0f + __expf(-acc[o]));
    }
}

// -------------------------------------------------------------------------
// Kernel 2: modulated deformable bilinear sampling. One thread per
// (bx, g, tap k, pixel): coords/weights computed once, reused across
// 16 channels x 2 y-halves (32 outputs). Mask folded into corner weights.
// -------------------------------------------------------------------------
__global__ __launch_bounds__(256) void sample_kernel(
    const float* __restrict__ y,
    const float* __restrict__ offs,
    const float* __restrict__ maskf,
    float* __restrict__ out)
{
    const int p  = blockIdx.x * 256 + threadIdx.x;  // pixel 0..16383
    const int bg = blockIdx.y;                      // 0..15
    const int bx = bg >> 2, g = bg & 3;
    const int k  = blockIdx.z;                      // tap 0..8
    const int h = p >> 7, w = p & 127;
    const int dil = 2 * g + 1;

    const long obase = ((long)(bx * 4 + g) * 18) * HWsz + p;
    const float dy = offs[obase + (long)(2 * k) * HWsz];
    const float dx = offs[obase + (long)(2 * k + 1) * HWsz];
    const float m  = maskf[((long)bx * 9 + k) * HWsz + p];

    const float py = (float)(h + (k / 3 - 1) * dil) + dy;
    const float px = (float)(w + (k % 3 - 1) * dil) + dx;
    const float y0f = floorf(py), x0f = floorf(px);
    const float wy = py - y0f, wx = px - x0f;
    const int y0 = (int)y0f, x0 = (int)x0f;
    const int y1 = y0 + 1, x1 = x0 + 1;
    const bool vy0 = (unsigned)y0 < 128u, vy1 = (unsigned)y1 < 128u;
    const bool vx0 = (unsigned)x0 < 128u, vx1 = (unsigned)x1 < 128u;
    // fold mask + validity into the 4 corner weights
    const float a00 = (vy0 && vx0) ? (1.f - wy) * (1.f - wx) * m : 0.f;
    const float a01 = (vy0 && vx1) ? (1.f - wy) * wx * m : 0.f;
    const float a10 = (vy1 && vx0) ? wy * (1.f - wx) * m : 0.f;
    const float a11 = (vy1 && vx1) ? wy * wx * m : 0.f;
    const int yc0 = min(max(y0, 0), 127), yc1 = min(max(y1, 0), 127);
    const int xc0 = min(max(x0, 0), 127), xc1 = min(max(x1, 0), 127);
    const int i00 = yc0 * 128 + xc0, i01 = yc0 * 128 + xc1;
    const int i10 = yc1 * 128 + xc0, i11 = yc1 * 128 + xc1;

    #pragma unroll
    for (int half = 0; half < 2; ++half) {
        const int b2 = bx + half * 4;              // y batch == out batch
        const float* yp = y + (long)(b2 * 64 + g * 16) * HWsz;
        float* op = out + ((long)(b2 * 64 + g * 16) * 9 + k) * HWsz + p;
        #pragma unroll
        for (int ci = 0; ci < 16; ++ci) {
            const float* pl = yp + (long)ci * HWsz;
            const float v = fmaf(pl[i00], a00,
                             fmaf(pl[i01], a01,
                              fmaf(pl[i10], a10, pl[i11] * a11)));
            op[(long)ci * 9 * HWsz] = v;
        }
    }
}

extern "C" void kernel_launch(void* const* d_in, const int* in_sizes, int n_in,
                              void* d_out, int out_size, void* d_ws, size_t ws_size,
                              hipStream_t stream) {
    const float* x       = (const float*)d_in[0];
    const float* y       = (const float*)d_in[1];
    const float* off_pw  = (const float*)d_in[2];
    const float* off_w   = (const float*)d_in[3];
    const float* off_b   = (const float*)d_in[4];
    const float* mask_pw = (const float*)d_in[5];
    const float* mask_w  = (const float*)d_in[6];
    const float* mask_b  = (const float*)d_in[7];
    float* out = (float*)d_out;

    float* ws        = (float*)d_ws;
    float* offs      = ws + OFFS_OFF;
    float* maskf     = ws + MASK_OFF;
    float* Weff_off  = ws + WEO_OFF;
    float* Wraw_off  = ws + WRO_OFF;
    float* Weff_mask = ws + WEM_OFF;
    float* Wraw_mask = ws + WRM_OFF;

    // 0) collapse weights (15552 work items)
    prep_kernel<<<61, 256, 0, stream>>>(off_pw, off_w, mask_pw, mask_w,
                                        Weff_off, Wraw_off, Weff_mask, Wraw_mask);
    // 1) offset + mask fields: 64 pixel-tiles x 4 batches x 5 passes
    field_kernel<<<dim3(64, 4, 5), 256, 0, stream>>>(
        x, Weff_off, Wraw_off, off_b, Weff_mask, Wraw_mask, mask_b, offs, maskf);
    // 2) deformable sampling: 64 pixel-tiles x 16 (bx,g) x 9 taps
    sample_kernel<<<dim3(64, 16, 9), 256, 0, stream>>>(y, offs, maskf, out);
}